// Round 9
// baseline (49.969 us; speedup 1.0000x reference)
//
#include <hip/hip_runtime.h>
#include <math.h>

#define NC 2048            // 2H + 2W (H = W = 512)
#define NB 4
#define NS 4096
#define INV_TEMP (1.0f / 256.0f)
#define LOG2E 1.44269504088896340736f
#define CL 16              // chunk length (scan-kernel granularity)
#define NCH (NS / CL)      // 256 chunks per batch
#define P1_NG 16           // scan groups per P1 block (512 thr / 32 ch)
#define P1_GS (NS / P1_NG) // 256 s per group
#define P1_GC (P1_GS / CL) // 16 chunks per group
#define LOSS_NBLK (NB * NCH)   // 1024 loss blocks

typedef float f32x4 __attribute__((ext_vector_type(4)));
typedef float f32x2 __attribute__((ext_vector_type(2)));

// ---------------------------------------------------------------------------
// Phase 1: per-(b, 32-channel tile) block.  (unchanged from R8, except it
// zeroes the loss kernel's block-counter instead of out[0])
// p in {0.0, 1.0} exactly: step s adds +1 at this block's segment channel
// (h or w) iff p[s]==(seg&1) -> pack {dec, enc} as float2 (enc = hot channel
// or -1) over the staged buffer; inner loop reads ds_read_b64.
// ---------------------------------------------------------------------------
__global__ __launch_bounds__(512) void tdl_scan_kernel(
    const float* __restrict__ target, float* __restrict__ rstart,
    int* __restrict__ counter)
{
    const int b     = blockIdx.x >> 6;   // 64 channel-tiles per batch
    const int ctile = blockIdx.x & 63;
    const int tid = threadIdx.x;
    const int ci  = tid & 31;            // channel within tile
    const int g   = tid >> 5;            // scan group (0..15)

    if (blockIdx.x == 0 && tid == 0) counter[0] = 0;  // reset epilogue counter

    __shared__ float shbuf[NS * 4];      // 64 KB: f32x4 ev[NS] then f32x2 pk[NS]
    __shared__ float shL[P1_NG][32];
    __shared__ float shG[P1_NG];
    f32x4* ev = (f32x4*)shbuf;
    f32x2* pk = (f32x2*)shbuf;

    const int  seg    = ctile >> 4;                       // 0..3
    const bool useH   = (seg < 2);
    const float segPar = (float)(seg & 1);
    const float crel  = (float)(((ctile & 15) << 5) + ci); // in-segment channel

    const float* tb = target + (size_t)b * NS * 4;

    // 1. stage target[b] as f32x4 {t,h,w,p}
#pragma unroll
    for (int m = 0; m < 8; ++m) {
        int s = m * 512 + tid;
        ev[s] = *((const f32x4*)tb + s);
    }
    __syncthreads();

    // 2. compute {dec, enc} in regs + my chunk alphas + group G (reads only)
    float dec_r[8], enc_r[8];
#pragma unroll
    for (int m = 0; m < 8; ++m) {
        int s = m * 512 + tid;
        f32x4 e = ev[s];
        dec_r[m] = (s == NS - 1) ? 0.0f
                  : __expf(-(ev[s + 1].x - e.x) * INV_TEMP);
        enc_r[m] = (e.w == segPar) ? (useH ? e.y : e.z) : -1.0f;
    }
    float alp[P1_GC];
    {
        const int gs = g * P1_GS;
#pragma unroll
        for (int q = 0; q < P1_GC; ++q) {
            int se = gs + q * CL;
            alp[q] = (g == P1_NG - 1 && q == P1_GC - 1) ? 0.0f
                     : __expf(-(ev[se + CL].x - ev[se].x) * INV_TEMP);
        }
        if (ci == 0) {
            shG[g] = (g == P1_NG - 1) ? 0.0f
                     : __expf(-(ev[gs + P1_GS].x - ev[gs].x) * INV_TEMP);
        }
    }
    __syncthreads();

    // 3. overwrite buffer with packed float2
#pragma unroll
    for (int m = 0; m < 8; ++m) {
        int s = m * 512 + tid;
        f32x2 v; v.x = dec_r[m]; v.y = enc_r[m];
        pk[s] = v;
    }
    __syncthreads();

    // 4. per-chunk local suffix sums (zero carry), 16 chunks in registers
    float cs[P1_GC];
    {
        const int gs = g * P1_GS;
#pragma unroll
        for (int q = P1_GC - 1; q >= 0; --q) {
            float v = 0.0f;
            const int base = gs + q * CL;
#pragma unroll
            for (int i = CL - 1; i >= 0; --i) {
                f32x2 e = pk[base + i];
                v = fmaf(v, e.x, (e.y == crel) ? 1.0f : 0.0f);
            }
            cs[q] = v;
        }
    }

    // 5. group-local combine -> L (value at group start, zero incoming)
    float L = 0.0f;
#pragma unroll
    for (int q = P1_GC - 1; q >= 0; --q) L = fmaf(alp[q], L, cs[q]);
    shL[g][ci] = L;
    __syncthreads();

    // 6. carry into group g = suffix over groups j > g
    float X = 0.0f;
#pragma unroll
    for (int j = P1_NG - 1; j >= 1; --j)
        if (j > g) X = fmaf(shG[j], X, shL[j][ci]);

    // 7. chunk-level replay with carry, store rstart[b, g*16+q, c]
    float* rs = rstart + ((size_t)b * NCH + g * P1_GC) * NC + (ctile * 32 + ci);
    float carry = X;
#pragma unroll
    for (int q = P1_GC - 1; q >= 0; --q) {
        carry = fmaf(alp[q], carry, cs[q]);
        rs[(size_t)q * NC] = carry;
    }
}

// ---------------------------------------------------------------------------
// Phase 2: fused scan + soft-CE loss, ACTIVE-SEGMENT ONLY (R8 structure).
// Epilogue CHANGED: no same-address atomicAdd burst. Each block stores its
// partial to partials[blk]; threadfence; relaxed fetch_add on counter; the
// block observing old == LOSS_NBLK-1 sums all partials and plain-stores
// out[0]. Removes the serialized 1024-deep same-line atomic tail.
// ---------------------------------------------------------------------------
__global__ __launch_bounds__(128) void tdl_loss_kernel(
    const float* __restrict__ pred, const float* __restrict__ target,
    const float* __restrict__ rstart, float* __restrict__ partials,
    int* __restrict__ counter, float* __restrict__ out)
{
    const int blk = blockIdx.x;
    const int b = blk >> 8;              // / NCH
    const int k = blk & (NCH - 1);
    const int s0 = k * CL;
    const int tid = threadIdx.x;
    const int wv  = tid >> 6;            // 0: H-pair, 1: W-pair
    const int ln  = tid & 63;

    __shared__ f32x4 ev[CL];             // {dec, p, h, w}
    __shared__ float sh2[2];
    __shared__ int   is_last;

    if (tid < CL) {
        const float* tg = target + ((size_t)b * NS + s0 + tid) * 4;
        float t0 = tg[0];
        int s = s0 + tid;
        float dec = (s == NS - 1 || s == 0) ? 0.0f
                   : __expf(-(tg[4] - t0) * INV_TEMP);   // tg[4] = t[s+1]
        f32x4 e; e.x = dec; e.y = tg[3]; e.z = tg[1]; e.w = tg[2];
        ev[tid] = e;
    }
    __syncthreads();

    const int lc   = ln * 4;             // lane offset within a 256-ch quarter
    const int segA = wv * 2;             // even segment of my pair
    const size_t pbase = (size_t)b * NS * NC;

    // scan state (exp2 domain) for both segments of the pair
    float vA[8], vB[8];
    if (k == NCH - 1) {
#pragma unroll
        for (int j = 0; j < 8; ++j) { vA[j] = 0.0f; vB[j] = 0.0f; }
    } else {
        const float* rrow = rstart + ((size_t)b * NCH + k + 1) * NC;
#pragma unroll
        for (int q = 0; q < 2; ++q) {
            f32x4 ra = *(const f32x4*)(rrow + segA * 512 + q * 256 + lc);
            f32x4 rb = *(const f32x4*)(rrow + (segA + 1) * 512 + q * 256 + lc);
#pragma unroll
            for (int j = 0; j < 4; ++j) {
                vA[q*4+j] = ra[j] * LOG2E;
                vB[q*4+j] = rb[j] * LOG2E;
            }
        }
    }

    // depth-2 prefetch of the ACTIVE segment's pred rows
    f32x4 pf0[2], pf1[2];
    {
        const int paT = (int)ev[CL - 1].y;
        const float* pr = pred + pbase + (size_t)(s0 + CL - 1) * NC
                          + (segA + paT) * 512 + lc;
        pf0[0] = *(const f32x4*)pr; pf0[1] = *(const f32x4*)(pr + 256);
        const int paU = (int)ev[CL - 2].y;
        const float* pr2 = pred + pbase + (size_t)(s0 + CL - 2) * NC
                           + (segA + paU) * 512 + lc;
        pf1[0] = *(const f32x4*)pr2; pf1[1] = *(const f32x4*)(pr2 + 256);
    }

    float acc = 0.0f;
#pragma unroll
    for (int i = CL - 1; i >= 0; --i) {
        f32x4 cur[2];
        cur[0] = pf0[0]; cur[1] = pf0[1];
        pf0[0] = pf1[0]; pf0[1] = pf1[1];
        if (i >= 2) {
            const int pa = (int)ev[i - 2].y;
            const float* pr = pred + pbase + (size_t)(s0 + i - 2) * NC
                              + (segA + pa) * 512 + lc;
            pf1[0] = *(const f32x4*)pr; pf1[1] = *(const f32x4*)(pr + 256);
        }

        f32x4 e = ev[i];
        const float d    = e.x;
        const float pv   = e.y;                    // 0.0 or 1.0 exactly
        const float idxf = wv ? e.w : e.z;         // w for W-pair, h for H-pair
        const float aA = (1.0f - pv) * LOG2E;      // add into even seg
        const float aB = pv * LOG2E;               // add into odd seg

        float ser = 0.0f, dot = 0.0f, sep = 0.0f;
#pragma unroll
        for (int q = 0; q < 2; ++q) {
#pragma unroll
            for (int j = 0; j < 4; ++j) {
                const int id = q * 4 + j;
                const float myc = (float)(q * 256 + lc + j);
                const bool m = (idxf == myc);
                vA[id] = fmaf(vA[id], d, m ? aA : 0.0f);  // scan both segs
                vB[id] = fmaf(vB[id], d, m ? aB : 0.0f);
                const float vs = (pv != 0.0f) ? vB[id] : vA[id];  // active
                const float ex = exp2f(vs);
                const float pj = cur[q][j];
                ser += ex;
                dot = fmaf(ex, pj, dot);
                sep += __expf(pj);
            }
        }
        // full-wave 64-lane reductions (active segment = 512 ch = 64 x 8)
#pragma unroll
        for (int off = 32; off > 0; off >>= 1) {
            ser += __shfl_xor(ser, off, 64);
            dot += __shfl_xor(dot, off, 64);
            sep += __shfl_xor(sep, off, 64);
        }
        acc += __logf(sep) - dot * __builtin_amdgcn_rcpf(ser);
    }

    if (ln == 0) sh2[wv] = acc;
    __syncthreads();

    // epilogue: partial store + counter; last block reduces
    if (tid == 0) {
        partials[blk] = sh2[0] + sh2[1];
        __threadfence();                           // release partials (agent)
        int old = __hip_atomic_fetch_add(counter, 1, __ATOMIC_RELAXED,
                                         __HIP_MEMORY_SCOPE_AGENT);
        is_last = (old == LOSS_NBLK - 1);
    }
    __syncthreads();

    if (is_last) {
        __threadfence();                           // acquire partials
        float s = 0.0f;
#pragma unroll
        for (int i = 0; i < LOSS_NBLK / 128; ++i)
            s += partials[i * 128 + tid];
#pragma unroll
        for (int off = 32; off > 0; off >>= 1)
            s += __shfl_xor(s, off, 64);
        if (ln == 0) sh2[wv] = s;
        __syncthreads();
        if (tid == 0)
            out[0] = (sh2[0] + sh2[1]) * (1.0f / ((float)NB * (float)NS));
    }
}

// ---------------------------------------------------------------------------
extern "C" void kernel_launch(void* const* d_in, const int* in_sizes, int n_in,
                              void* d_out, int out_size, void* d_ws, size_t ws_size,
                              hipStream_t stream)
{
    const float* pred   = (const float*)d_in[0];
    const float* target = (const float*)d_in[1];
    float* out    = (float*)d_out;
    float* rstart = (float*)d_ws;                       // 8 MiB
    float* partials = rstart + (size_t)NB * NCH * NC;   // 4 KiB
    int*   counter  = (int*)(partials + LOSS_NBLK);     // 4 B

    tdl_scan_kernel<<<NB * 64, 512, 0, stream>>>(target, rstart, counter);
    tdl_loss_kernel<<<NB * NCH, 128, 0, stream>>>(pred, target, rstart,
                                                  partials, counter, out);
}

// Round 10
// 36.923 us; speedup vs baseline: 1.3534x; 1.3534x over previous
//
#include <hip/hip_runtime.h>
#include <math.h>

#define NC 2048            // 2H + 2W (H = W = 512)
#define NB 4
#define NS 4096
#define INV_TEMP (1.0f / 256.0f)
#define LOG2E 1.44269504088896340736f
#define CL 16              // chunk length (scan-kernel granularity)
#define NCH (NS / CL)      // 256 chunks per batch
#define P1_NG 16           // scan groups per P1 block (512 thr / 32 ch)
#define P1_GS (NS / P1_NG) // 256 s per group
#define P1_GC (P1_GS / CL) // 16 chunks per group

typedef float f32x4 __attribute__((ext_vector_type(4)));
typedef float f32x2 __attribute__((ext_vector_type(2)));

// ---------------------------------------------------------------------------
// Phase 1: per-(b, 32-channel tile) block.  (identical to R8)
// p in {0.0, 1.0} exactly: step s adds +1 at this block's segment channel
// (h or w) iff p[s]==(seg&1) -> pack {dec, enc} as float2 (enc = hot channel
// or -1) over the staged buffer; inner loop reads ds_read_b64.
// ---------------------------------------------------------------------------
__global__ __launch_bounds__(512) void tdl_scan_kernel(
    const float* __restrict__ target, float* __restrict__ rstart,
    float* __restrict__ out)
{
    const int b     = blockIdx.x >> 6;   // 64 channel-tiles per batch
    const int ctile = blockIdx.x & 63;
    const int tid = threadIdx.x;
    const int ci  = tid & 31;            // channel within tile
    const int g   = tid >> 5;            // scan group (0..15)

    if (blockIdx.x == 0 && tid == 0) out[0] = 0.0f;  // zero loss accumulator

    __shared__ float shbuf[NS * 4];      // 64 KB: f32x4 ev[NS] then f32x2 pk[NS]
    __shared__ float shL[P1_NG][32];
    __shared__ float shG[P1_NG];
    f32x4* ev = (f32x4*)shbuf;
    f32x2* pk = (f32x2*)shbuf;

    const int  seg    = ctile >> 4;                       // 0..3
    const bool useH   = (seg < 2);
    const float segPar = (float)(seg & 1);
    const float crel  = (float)(((ctile & 15) << 5) + ci); // in-segment channel

    const float* tb = target + (size_t)b * NS * 4;

    // 1. stage target[b] as f32x4 {t,h,w,p}
#pragma unroll
    for (int m = 0; m < 8; ++m) {
        int s = m * 512 + tid;
        ev[s] = *((const f32x4*)tb + s);
    }
    __syncthreads();

    // 2. compute {dec, enc} in regs + my chunk alphas + group G (reads only)
    float dec_r[8], enc_r[8];
#pragma unroll
    for (int m = 0; m < 8; ++m) {
        int s = m * 512 + tid;
        f32x4 e = ev[s];
        dec_r[m] = (s == NS - 1) ? 0.0f
                  : __expf(-(ev[s + 1].x - e.x) * INV_TEMP);
        enc_r[m] = (e.w == segPar) ? (useH ? e.y : e.z) : -1.0f;
    }
    float alp[P1_GC];
    {
        const int gs = g * P1_GS;
#pragma unroll
        for (int q = 0; q < P1_GC; ++q) {
            int se = gs + q * CL;
            alp[q] = (g == P1_NG - 1 && q == P1_GC - 1) ? 0.0f
                     : __expf(-(ev[se + CL].x - ev[se].x) * INV_TEMP);
        }
        if (ci == 0) {
            shG[g] = (g == P1_NG - 1) ? 0.0f
                     : __expf(-(ev[gs + P1_GS].x - ev[gs].x) * INV_TEMP);
        }
    }
    __syncthreads();

    // 3. overwrite buffer with packed float2
#pragma unroll
    for (int m = 0; m < 8; ++m) {
        int s = m * 512 + tid;
        f32x2 v; v.x = dec_r[m]; v.y = enc_r[m];
        pk[s] = v;
    }
    __syncthreads();

    // 4. per-chunk local suffix sums (zero carry), 16 chunks in registers
    float cs[P1_GC];
    {
        const int gs = g * P1_GS;
#pragma unroll
        for (int q = P1_GC - 1; q >= 0; --q) {
            float v = 0.0f;
            const int base = gs + q * CL;
#pragma unroll
            for (int i = CL - 1; i >= 0; --i) {
                f32x2 e = pk[base + i];
                v = fmaf(v, e.x, (e.y == crel) ? 1.0f : 0.0f);
            }
            cs[q] = v;
        }
    }

    // 5. group-local combine -> L (value at group start, zero incoming)
    float L = 0.0f;
#pragma unroll
    for (int q = P1_GC - 1; q >= 0; --q) L = fmaf(alp[q], L, cs[q]);
    shL[g][ci] = L;
    __syncthreads();

    // 6. carry into group g = suffix over groups j > g
    float X = 0.0f;
#pragma unroll
    for (int j = P1_NG - 1; j >= 1; --j)
        if (j > g) X = fmaf(shG[j], X, shL[j][ci]);

    // 7. chunk-level replay with carry, store rstart[b, g*16+q, c]
    float* rs = rstart + ((size_t)b * NCH + g * P1_GC) * NC + (ctile * 32 + ci);
    float carry = X;
#pragma unroll
    for (int q = P1_GC - 1; q >= 0; --q) {
        carry = fmaf(alp[q], carry, cs[q]);
        rs[(size_t)q * NC] = carry;
    }
}

// ---------------------------------------------------------------------------
// Phase 2: fused scan + soft-CE loss, ACTIVE-SEGMENT ONLY (R8 math), now with
// 4 waves per block for 2x TLP (4 waves/SIMD instead of 2):
//   wave 0: H-pair rows 15..8     wave 1: W-pair rows 15..8
//   wave 2: H-pair rows  7..0     wave 3: W-pair rows  7..0
// Waves 2,3 first replay rows 15..8 scan-only (fma-only, no memory) to derive
// their carry. One ev staging, one atomicAdd per block (R8 epilogue — the
// R9 partials+threadfence variant regressed 11 us via L2 writebacks).
// ---------------------------------------------------------------------------
__global__ __launch_bounds__(256) void tdl_loss_kernel(
    const float* __restrict__ pred, const float* __restrict__ target,
    const float* __restrict__ rstart, float* __restrict__ out)
{
    const int blk = blockIdx.x;
    const int b = blk >> 8;              // / NCH
    const int k = blk & (NCH - 1);
    const int s0 = k * CL;
    const int tid = threadIdx.x;
    const int wv  = (tid >> 6) & 1;      // 0: H-pair, 1: W-pair
    const int rh  = tid >> 7;            // 0: rows 15..8, 1: rows 7..0
    const int ln  = tid & 63;

    __shared__ f32x4 ev[CL];             // {dec, p, h, w}
    __shared__ float sh4[4];

    if (tid < CL) {
        const float* tg = target + ((size_t)b * NS + s0 + tid) * 4;
        float t0 = tg[0];
        int s = s0 + tid;
        float dec = (s == NS - 1 || s == 0) ? 0.0f
                   : __expf(-(tg[4] - t0) * INV_TEMP);   // tg[4] = t[s+1]
        f32x4 e; e.x = dec; e.y = tg[3]; e.z = tg[1]; e.w = tg[2];
        ev[tid] = e;
    }
    __syncthreads();

    const int lc   = ln * 4;             // lane offset within a 256-ch quarter
    const int segA = wv * 2;             // even segment of my pair
    const size_t pbase = (size_t)b * NS * NC;

    // scan state (exp2 domain) for both segments of the pair
    float vA[8], vB[8];
    if (k == NCH - 1) {
#pragma unroll
        for (int j = 0; j < 8; ++j) { vA[j] = 0.0f; vB[j] = 0.0f; }
    } else {
        const float* rrow = rstart + ((size_t)b * NCH + k + 1) * NC;
#pragma unroll
        for (int q = 0; q < 2; ++q) {
            f32x4 ra = *(const f32x4*)(rrow + segA * 512 + q * 256 + lc);
            f32x4 rb = *(const f32x4*)(rrow + (segA + 1) * 512 + q * 256 + lc);
#pragma unroll
            for (int j = 0; j < 4; ++j) {
                vA[q*4+j] = ra[j] * LOG2E;
                vB[q*4+j] = rb[j] * LOG2E;
            }
        }
    }

    // lower-half waves: replay rows 15..8 scan-only to derive carry at row 8
    if (rh) {
#pragma unroll
        for (int i = CL - 1; i >= 8; --i) {
            f32x4 e = ev[i];
            const float d    = e.x;
            const float pv   = e.y;
            const float idxf = wv ? e.w : e.z;
            const float aA = (1.0f - pv) * LOG2E;
            const float aB = pv * LOG2E;
#pragma unroll
            for (int q = 0; q < 2; ++q) {
#pragma unroll
                for (int j = 0; j < 4; ++j) {
                    const int id = q * 4 + j;
                    const float myc = (float)(q * 256 + lc + j);
                    const bool m = (idxf == myc);
                    vA[id] = fmaf(vA[id], d, m ? aA : 0.0f);
                    vB[id] = fmaf(vB[id], d, m ? aB : 0.0f);
                }
            }
        }
    }

    const int itop = rh ? 7 : (CL - 1);  // my 8 loss rows: itop .. itop-7

    // depth-2 prefetch of the ACTIVE segment's pred rows
    f32x4 pf0[2], pf1[2];
    {
        const int paT = (int)ev[itop].y;
        const float* pr = pred + pbase + (size_t)(s0 + itop) * NC
                          + (segA + paT) * 512 + lc;
        pf0[0] = *(const f32x4*)pr; pf0[1] = *(const f32x4*)(pr + 256);
        const int paU = (int)ev[itop - 1].y;
        const float* pr2 = pred + pbase + (size_t)(s0 + itop - 1) * NC
                           + (segA + paU) * 512 + lc;
        pf1[0] = *(const f32x4*)pr2; pf1[1] = *(const f32x4*)(pr2 + 256);
    }

    float acc = 0.0f;
#pragma unroll
    for (int i = itop; i > itop - 8; --i) {
        f32x4 cur[2];
        cur[0] = pf0[0]; cur[1] = pf0[1];
        pf0[0] = pf1[0]; pf0[1] = pf1[1];
        if (i >= itop - 5) {             // row i-2 still in my range
            const int pa = (int)ev[i - 2].y;
            const float* pr = pred + pbase + (size_t)(s0 + i - 2) * NC
                              + (segA + pa) * 512 + lc;
            pf1[0] = *(const f32x4*)pr; pf1[1] = *(const f32x4*)(pr + 256);
        }

        f32x4 e = ev[i];
        const float d    = e.x;
        const float pv   = e.y;                    // 0.0 or 1.0 exactly
        const float idxf = wv ? e.w : e.z;         // w for W-pair, h for H-pair
        const float aA = (1.0f - pv) * LOG2E;      // add into even seg
        const float aB = pv * LOG2E;               // add into odd seg

        float ser = 0.0f, dot = 0.0f, sep = 0.0f;
#pragma unroll
        for (int q = 0; q < 2; ++q) {
#pragma unroll
            for (int j = 0; j < 4; ++j) {
                const int id = q * 4 + j;
                const float myc = (float)(q * 256 + lc + j);
                const bool m = (idxf == myc);
                vA[id] = fmaf(vA[id], d, m ? aA : 0.0f);  // scan both segs
                vB[id] = fmaf(vB[id], d, m ? aB : 0.0f);
                const float vs = (pv != 0.0f) ? vB[id] : vA[id];  // active
                const float ex = exp2f(vs);
                const float pj = cur[q][j];
                ser += ex;
                dot = fmaf(ex, pj, dot);
                sep += __expf(pj);
            }
        }
        // full-wave 64-lane reductions (active segment = 512 ch = 64 x 8)
#pragma unroll
        for (int off = 32; off > 0; off >>= 1) {
            ser += __shfl_xor(ser, off, 64);
            dot += __shfl_xor(dot, off, 64);
            sep += __shfl_xor(sep, off, 64);
        }
        acc += __logf(sep) - dot * __builtin_amdgcn_rcpf(ser);
    }

    if (ln == 0) sh4[tid >> 6] = acc;    // one writer per wave
    __syncthreads();
    if (tid == 0) {
        float tot = (sh4[0] + sh4[1] + sh4[2] + sh4[3])
                    * (1.0f / ((float)NB * (float)NS));
        atomicAdd(out, tot);
    }
}

// ---------------------------------------------------------------------------
extern "C" void kernel_launch(void* const* d_in, const int* in_sizes, int n_in,
                              void* d_out, int out_size, void* d_ws, size_t ws_size,
                              hipStream_t stream)
{
    const float* pred   = (const float*)d_in[0];
    const float* target = (const float*)d_in[1];
    float* out    = (float*)d_out;
    float* rstart = (float*)d_ws;   // NB*NCH*NC floats = 8 MiB

    tdl_scan_kernel<<<NB * 64, 512, 0, stream>>>(target, rstart, out);
    tdl_loss_kernel<<<NB * NCH, 256, 0, stream>>>(pred, target, rstart, out);
}

// Round 11
// 31.758 us; speedup vs baseline: 1.5734x; 1.1626x over previous
//
#include <hip/hip_runtime.h>
#include <math.h>

#define NC 2048            // 2H + 2W (H = W = 512)
#define NB 4
#define NS 4096
#define INV_TEMP (1.0f / 256.0f)
#define LOG2E 1.44269504088896340736f
#define CL 16              // chunk length (scan-kernel granularity)
#define NCH (NS / CL)      // 256 chunks per batch
#define P1_NG 16           // scan groups per P1 block (512 thr / 32 ch)
#define P1_GS (NS / P1_NG) // 256 s per group
#define P1_GC (P1_GS / CL) // 16 chunks per group
#define LOSS_NBLK (NB * NCH)   // 1024 loss blocks

typedef float f32x4 __attribute__((ext_vector_type(4)));
typedef float f32x2 __attribute__((ext_vector_type(2)));

// ---------------------------------------------------------------------------
// Phase 1: per-(b, 32-channel tile) block.  (identical to R10, minus the
// out-zeroing — out is now written by a plain store in the reduce kernel)
// ---------------------------------------------------------------------------
__global__ __launch_bounds__(512) void tdl_scan_kernel(
    const float* __restrict__ target, float* __restrict__ rstart)
{
    const int b     = blockIdx.x >> 6;   // 64 channel-tiles per batch
    const int ctile = blockIdx.x & 63;
    const int tid = threadIdx.x;
    const int ci  = tid & 31;            // channel within tile
    const int g   = tid >> 5;            // scan group (0..15)

    __shared__ float shbuf[NS * 4];      // 64 KB: f32x4 ev[NS] then f32x2 pk[NS]
    __shared__ float shL[P1_NG][32];
    __shared__ float shG[P1_NG];
    f32x4* ev = (f32x4*)shbuf;
    f32x2* pk = (f32x2*)shbuf;

    const int  seg    = ctile >> 4;                       // 0..3
    const bool useH   = (seg < 2);
    const float segPar = (float)(seg & 1);
    const float crel  = (float)(((ctile & 15) << 5) + ci); // in-segment channel

    const float* tb = target + (size_t)b * NS * 4;

    // 1. stage target[b] as f32x4 {t,h,w,p}
#pragma unroll
    for (int m = 0; m < 8; ++m) {
        int s = m * 512 + tid;
        ev[s] = *((const f32x4*)tb + s);
    }
    __syncthreads();

    // 2. compute {dec, enc} in regs + my chunk alphas + group G (reads only)
    float dec_r[8], enc_r[8];
#pragma unroll
    for (int m = 0; m < 8; ++m) {
        int s = m * 512 + tid;
        f32x4 e = ev[s];
        dec_r[m] = (s == NS - 1) ? 0.0f
                  : __expf(-(ev[s + 1].x - e.x) * INV_TEMP);
        enc_r[m] = (e.w == segPar) ? (useH ? e.y : e.z) : -1.0f;
    }
    float alp[P1_GC];
    {
        const int gs = g * P1_GS;
#pragma unroll
        for (int q = 0; q < P1_GC; ++q) {
            int se = gs + q * CL;
            alp[q] = (g == P1_NG - 1 && q == P1_GC - 1) ? 0.0f
                     : __expf(-(ev[se + CL].x - ev[se].x) * INV_TEMP);
        }
        if (ci == 0) {
            shG[g] = (g == P1_NG - 1) ? 0.0f
                     : __expf(-(ev[gs + P1_GS].x - ev[gs].x) * INV_TEMP);
        }
    }
    __syncthreads();

    // 3. overwrite buffer with packed float2
#pragma unroll
    for (int m = 0; m < 8; ++m) {
        int s = m * 512 + tid;
        f32x2 v; v.x = dec_r[m]; v.y = enc_r[m];
        pk[s] = v;
    }
    __syncthreads();

    // 4. per-chunk local suffix sums (zero carry), 16 chunks in registers
    float cs[P1_GC];
    {
        const int gs = g * P1_GS;
#pragma unroll
        for (int q = P1_GC - 1; q >= 0; --q) {
            float v = 0.0f;
            const int base = gs + q * CL;
#pragma unroll
            for (int i = CL - 1; i >= 0; --i) {
                f32x2 e = pk[base + i];
                v = fmaf(v, e.x, (e.y == crel) ? 1.0f : 0.0f);
            }
            cs[q] = v;
        }
    }

    // 5. group-local combine -> L (value at group start, zero incoming)
    float L = 0.0f;
#pragma unroll
    for (int q = P1_GC - 1; q >= 0; --q) L = fmaf(alp[q], L, cs[q]);
    shL[g][ci] = L;
    __syncthreads();

    // 6. carry into group g = suffix over groups j > g
    float X = 0.0f;
#pragma unroll
    for (int j = P1_NG - 1; j >= 1; --j)
        if (j > g) X = fmaf(shG[j], X, shL[j][ci]);

    // 7. chunk-level replay with carry, store rstart[b, g*16+q, c]
    float* rs = rstart + ((size_t)b * NCH + g * P1_GC) * NC + (ctile * 32 + ci);
    float carry = X;
#pragma unroll
    for (int q = P1_GC - 1; q >= 0; --q) {
        carry = fmaf(alp[q], carry, cs[q]);
        rs[(size_t)q * NC] = carry;
    }
}

// ---------------------------------------------------------------------------
// Phase 2: fused scan + soft-CE loss, ACTIVE-SEGMENT ONLY, 4 waves/block
// (R10 structure). Epilogue CHANGED: plain store of the block partial to
// partials[blk] — no atomics, no fences. The 1024 same-address device-scope
// atomicAdds formed a serialized RMW tail at the coherence point that
// dispatch-end had to drain (suspected ~10+ us, unhidden by TLP).
// ---------------------------------------------------------------------------
__global__ __launch_bounds__(256) void tdl_loss_kernel(
    const float* __restrict__ pred, const float* __restrict__ target,
    const float* __restrict__ rstart, float* __restrict__ partials)
{
    const int blk = blockIdx.x;
    const int b = blk >> 8;              // / NCH
    const int k = blk & (NCH - 1);
    const int s0 = k * CL;
    const int tid = threadIdx.x;
    const int wv  = (tid >> 6) & 1;      // 0: H-pair, 1: W-pair
    const int rh  = tid >> 7;            // 0: rows 15..8, 1: rows 7..0
    const int ln  = tid & 63;

    __shared__ f32x4 ev[CL];             // {dec, p, h, w}
    __shared__ float sh4[4];

    if (tid < CL) {
        const float* tg = target + ((size_t)b * NS + s0 + tid) * 4;
        float t0 = tg[0];
        int s = s0 + tid;
        float dec = (s == NS - 1 || s == 0) ? 0.0f
                   : __expf(-(tg[4] - t0) * INV_TEMP);   // tg[4] = t[s+1]
        f32x4 e; e.x = dec; e.y = tg[3]; e.z = tg[1]; e.w = tg[2];
        ev[tid] = e;
    }
    __syncthreads();

    const int lc   = ln * 4;             // lane offset within a 256-ch quarter
    const int segA = wv * 2;             // even segment of my pair
    const size_t pbase = (size_t)b * NS * NC;

    // scan state (exp2 domain) for both segments of the pair
    float vA[8], vB[8];
    if (k == NCH - 1) {
#pragma unroll
        for (int j = 0; j < 8; ++j) { vA[j] = 0.0f; vB[j] = 0.0f; }
    } else {
        const float* rrow = rstart + ((size_t)b * NCH + k + 1) * NC;
#pragma unroll
        for (int q = 0; q < 2; ++q) {
            f32x4 ra = *(const f32x4*)(rrow + segA * 512 + q * 256 + lc);
            f32x4 rb = *(const f32x4*)(rrow + (segA + 1) * 512 + q * 256 + lc);
#pragma unroll
            for (int j = 0; j < 4; ++j) {
                vA[q*4+j] = ra[j] * LOG2E;
                vB[q*4+j] = rb[j] * LOG2E;
            }
        }
    }

    // lower-half waves: replay rows 15..8 scan-only to derive carry at row 8
    if (rh) {
#pragma unroll
        for (int i = CL - 1; i >= 8; --i) {
            f32x4 e = ev[i];
            const float d    = e.x;
            const float pv   = e.y;
            const float idxf = wv ? e.w : e.z;
            const float aA = (1.0f - pv) * LOG2E;
            const float aB = pv * LOG2E;
#pragma unroll
            for (int q = 0; q < 2; ++q) {
#pragma unroll
                for (int j = 0; j < 4; ++j) {
                    const int id = q * 4 + j;
                    const float myc = (float)(q * 256 + lc + j);
                    const bool m = (idxf == myc);
                    vA[id] = fmaf(vA[id], d, m ? aA : 0.0f);
                    vB[id] = fmaf(vB[id], d, m ? aB : 0.0f);
                }
            }
        }
    }

    const int itop = rh ? 7 : (CL - 1);  // my 8 loss rows: itop .. itop-7

    // depth-2 prefetch of the ACTIVE segment's pred rows
    f32x4 pf0[2], pf1[2];
    {
        const int paT = (int)ev[itop].y;
        const float* pr = pred + pbase + (size_t)(s0 + itop) * NC
                          + (segA + paT) * 512 + lc;
        pf0[0] = *(const f32x4*)pr; pf0[1] = *(const f32x4*)(pr + 256);
        const int paU = (int)ev[itop - 1].y;
        const float* pr2 = pred + pbase + (size_t)(s0 + itop - 1) * NC
                           + (segA + paU) * 512 + lc;
        pf1[0] = *(const f32x4*)pr2; pf1[1] = *(const f32x4*)(pr2 + 256);
    }

    float acc = 0.0f;
#pragma unroll
    for (int i = itop; i > itop - 8; --i) {
        f32x4 cur[2];
        cur[0] = pf0[0]; cur[1] = pf0[1];
        pf0[0] = pf1[0]; pf0[1] = pf1[1];
        if (i >= itop - 5) {             // row i-2 still in my range
            const int pa = (int)ev[i - 2].y;
            const float* pr = pred + pbase + (size_t)(s0 + i - 2) * NC
                              + (segA + pa) * 512 + lc;
            pf1[0] = *(const f32x4*)pr; pf1[1] = *(const f32x4*)(pr + 256);
        }

        f32x4 e = ev[i];
        const float d    = e.x;
        const float pv   = e.y;                    // 0.0 or 1.0 exactly
        const float idxf = wv ? e.w : e.z;         // w for W-pair, h for H-pair
        const float aA = (1.0f - pv) * LOG2E;      // add into even seg
        const float aB = pv * LOG2E;               // add into odd seg

        float ser = 0.0f, dot = 0.0f, sep = 0.0f;
#pragma unroll
        for (int q = 0; q < 2; ++q) {
#pragma unroll
            for (int j = 0; j < 4; ++j) {
                const int id = q * 4 + j;
                const float myc = (float)(q * 256 + lc + j);
                const bool m = (idxf == myc);
                vA[id] = fmaf(vA[id], d, m ? aA : 0.0f);  // scan both segs
                vB[id] = fmaf(vB[id], d, m ? aB : 0.0f);
                const float vs = (pv != 0.0f) ? vB[id] : vA[id];  // active
                const float ex = exp2f(vs);
                const float pj = cur[q][j];
                ser += ex;
                dot = fmaf(ex, pj, dot);
                sep += __expf(pj);
            }
        }
        // full-wave 64-lane reductions (active segment = 512 ch = 64 x 8)
#pragma unroll
        for (int off = 32; off > 0; off >>= 1) {
            ser += __shfl_xor(ser, off, 64);
            dot += __shfl_xor(dot, off, 64);
            sep += __shfl_xor(sep, off, 64);
        }
        acc += __logf(sep) - dot * __builtin_amdgcn_rcpf(ser);
    }

    if (ln == 0) sh4[tid >> 6] = acc;    // one writer per wave
    __syncthreads();
    if (tid == 0) partials[blk] = sh4[0] + sh4[1] + sh4[2] + sh4[3];
}

// ---------------------------------------------------------------------------
// Phase 3: tiny reduce — 1 block, 256 threads, 4 KB of partials -> out[0].
// Kernel-boundary ordering guarantees partials visibility (no fences).
// ---------------------------------------------------------------------------
__global__ __launch_bounds__(256) void tdl_reduce_kernel(
    const float* __restrict__ partials, float* __restrict__ out)
{
    const int tid = threadIdx.x;
    __shared__ float sh4[4];

    float s = 0.0f;
#pragma unroll
    for (int i = 0; i < LOSS_NBLK / 256; ++i)
        s += partials[i * 256 + tid];
#pragma unroll
    for (int off = 32; off > 0; off >>= 1)
        s += __shfl_xor(s, off, 64);
    if ((tid & 63) == 0) sh4[tid >> 6] = s;
    __syncthreads();
    if (tid == 0)
        out[0] = (sh4[0] + sh4[1] + sh4[2] + sh4[3])
                 * (1.0f / ((float)NB * (float)NS));
}

// ---------------------------------------------------------------------------
extern "C" void kernel_launch(void* const* d_in, const int* in_sizes, int n_in,
                              void* d_out, int out_size, void* d_ws, size_t ws_size,
                              hipStream_t stream)
{
    const float* pred   = (const float*)d_in[0];
    const float* target = (const float*)d_in[1];
    float* out    = (float*)d_out;
    float* rstart = (float*)d_ws;                       // 8 MiB
    float* partials = rstart + (size_t)NB * NCH * NC;   // 4 KiB

    tdl_scan_kernel<<<NB * 64, 512, 0, stream>>>(target, rstart);
    tdl_loss_kernel<<<NB * NCH, 256, 0, stream>>>(pred, target, rstart, partials);
    tdl_reduce_kernel<<<1, 256, 0, stream>>>(partials, out);
}